// Round 4
// baseline (500.392 us; speedup 1.0000x reference)
//
#include <hip/hip_runtime.h>
#include <math.h>

#define N_EDGES 65536
#define LNODE 512
#define DSTATE 256
#define DINNER 256
#define HEADD 64

using bf16x8 = __attribute__((ext_vector_type(8))) short;
using f32x4  = __attribute__((ext_vector_type(4))) float;
using us4    = __attribute__((ext_vector_type(4))) unsigned short;

__device__ __forceinline__ float softplusf(float z) {
  return (z > 0.0f) ? (z + log1pf(expf(-z))) : log1pf(expf(z));
}
__device__ __forceinline__ float bf2f(unsigned short u) {
  unsigned int x = ((unsigned int)u) << 16;
  return __builtin_bit_cast(float, x);
}
__device__ __forceinline__ unsigned short f2bf(float f) {
  unsigned int x = __builtin_bit_cast(unsigned int, f);
  x += 0x7fffu + ((x >> 16) & 1u);
  return (unsigned short)(x >> 16);
}

// ---------------------------------------------------------------------------
// Scatter edges into G = A^T (per (graph,head) 512x512), G[l2][l1] += val,
// plus column sums colsum[bn][l1] += val.
// ---------------------------------------------------------------------------
__global__ void scatter_edges_kernel(const float* __restrict__ dt,
                                     const float* __restrict__ dt_edge,
                                     const float* __restrict__ dt_bias,
                                     const int* __restrict__ edge_index,
                                     float* __restrict__ G,
                                     float* __restrict__ colsum) {
  int t = blockIdx.x * blockDim.x + threadIdx.x;
  if (t >= N_EDGES * 4) return;
  int e = t >> 2;
  int n = t & 3;
  int src = edge_index[e];
  int dst = edge_index[N_EDGES + e];
  float bias = dt_bias[n];
  float z0 = dt[src * 16 + n * 4 + 0] + bias;
  float z1 = dt[dst * 16 + n * 4 + 1] + bias;
  float z2 = dt_edge[e * 4 + n] + bias;
  float val = expf(-(softplusf(z0) + softplusf(z1) + softplusf(z2)) * (1.0f / 3.0f));
  int b = src >> 9;
  int l1 = src & 511;
  int l2 = dst & 511;
  int bn = b * 4 + n;
  atomicAdd(&G[(((size_t)bn) << 18) + ((size_t)l2 << 9) + l1], val);
  atomicAdd(&colsum[bn * 512 + l1], val);
}

// ---------------------------------------------------------------------------
// Convert + normalize: v = G * inv(col); Prm = bf16(v), Pt = bf16(v^T),
// Q = bf16(I + v). 32x32 tiles.
// ---------------------------------------------------------------------------
__global__ __launch_bounds__(256) void conv_kernel(const float* __restrict__ G,
                                                   const float* __restrict__ colsum,
                                                   const float* __restrict__ dt,
                                                   const float* __restrict__ dt_bias,
                                                   unsigned short* __restrict__ Prm,
                                                   unsigned short* __restrict__ Pt,
                                                   unsigned short* __restrict__ Q) {
  const int bn = blockIdx.y;
  const int n = bn & 3, b = bn >> 2;
  const size_t base = (size_t)bn << 18;
  const int tile = blockIdx.x;
  const int ro = (tile >> 4) << 5;
  const int co = (tile & 15) << 5;
  __shared__ float lds[32][33];
  __shared__ float sinv[32];
  const int t = threadIdx.x;
  if (t < 32) {
    const int col = co + t;
    float ssum = colsum[bn * 512 + col];
    float bias = dt_bias[n];
    float dummy = expf(-softplusf(dt[(size_t)(b * 512 + col) * 16 + n * 4 + 2] + bias));
    float norm = fmaxf(1.0f, ssum + dummy);
    sinv[t] = 1.0f / (norm + 0.05f);
  }
  __syncthreads();
  const int tr = t >> 3;
  const int tc0 = (t & 7) << 2;
  float4 gv = *(const float4*)(G + base + (size_t)(ro + tr) * 512 + co + tc0);
  float vv[4] = {gv.x, gv.y, gv.z, gv.w};
  us4 p, q;
#pragma unroll
  for (int j = 0; j < 4; ++j) {
    vv[j] *= sinv[tc0 + j];
    p[j] = f2bf(vv[j]);
    float qq = vv[j] + (((ro + tr) == (co + tc0 + j)) ? 1.0f : 0.0f);
    q[j] = f2bf(qq);
    lds[tc0 + j][tr] = vv[j];
  }
  *(us4*)(Prm + base + (size_t)(ro + tr) * 512 + co + tc0) = p;
  *(us4*)(Q + base + (size_t)(ro + tr) * 512 + co + tc0) = q;
  __syncthreads();
  us4 pt;
#pragma unroll
  for (int j = 0; j < 4; ++j) pt[j] = f2bf(lds[tr][tc0 + j]);
  *(us4*)(Pt + base + (size_t)(co + tr) * 512 + ro + tc0) = pt;
}

// ---------------------------------------------------------------------------
// Paired batched bf16 MFMA GEMM: z = blockIdx.z selects operand set.
// C = A @ B (+ Qadd if non-null), B given transposed ([N][K]).
// Writes Crm (row-major) and/or Ct (transposed) if non-null.
// 128x128 tile, BK=64, 4 waves, global_load_lds, XOR-swizzled LDS.
// ---------------------------------------------------------------------------
__global__ __launch_bounds__(256) void gemm_pair_kernel(
    const unsigned short* __restrict__ A0, const unsigned short* __restrict__ B0,
    unsigned short* __restrict__ C0rm, unsigned short* __restrict__ C0t,
    const unsigned short* __restrict__ Q0,
    const unsigned short* __restrict__ A1, const unsigned short* __restrict__ B1,
    unsigned short* __restrict__ C1rm, unsigned short* __restrict__ C1t,
    const unsigned short* __restrict__ Q1) {
  const int z = blockIdx.z;
  const unsigned short* A    = z ? A1 : A0;
  const unsigned short* Bt   = z ? B1 : B0;
  unsigned short* Crm        = z ? C1rm : C0rm;
  unsigned short* Ct         = z ? C1t : C0t;
  const unsigned short* Qadd = z ? Q1 : Q0;

  const int bn = blockIdx.y;
  const size_t off = (size_t)bn << 18;
  A += off; Bt += off;
  if (Crm) Crm += off;
  if (Ct) Ct += off;
  if (Qadd) Qadd += off;
  const int m0 = (blockIdx.x >> 2) << 7;
  const int n0 = (blockIdx.x & 3) << 7;
  __shared__ __align__(16) char lds[32768];
  char* ldsA = lds;
  char* ldsB = lds + 16384;
  const int tid = threadIdx.x;
  const int lane = tid & 63;
  const int w = tid >> 6;
  const int wr = w >> 1, wc = w & 1;
  const int lr = lane >> 3, g = lane & 7;

  f32x4 acc[4][4];
#pragma unroll
  for (int i = 0; i < 4; ++i)
#pragma unroll
    for (int j = 0; j < 4; ++j) acc[i][j] = (f32x4)(0.0f);

  for (int k0 = 0; k0 < 512; k0 += 64) {
#pragma unroll
    for (int s = 0; s < 4; ++s) {
      const int r = s * 32 + w * 8 + lr;
      const unsigned short* ga = A + (size_t)(m0 + r) * 512 + k0 + ((g ^ (r & 7)) << 3);
      __builtin_amdgcn_global_load_lds(
          (const __attribute__((address_space(1))) void*)ga,
          (__attribute__((address_space(3))) void*)(ldsA + s * 4096 + w * 1024 + (lane << 4)),
          16, 0, 0);
      const unsigned short* gb = Bt + (size_t)(n0 + r) * 512 + k0 + ((g ^ (r & 7)) << 3);
      __builtin_amdgcn_global_load_lds(
          (const __attribute__((address_space(1))) void*)gb,
          (__attribute__((address_space(3))) void*)(ldsB + s * 4096 + w * 1024 + (lane << 4)),
          16, 0, 0);
    }
    __syncthreads();
#pragma unroll
    for (int kk = 0; kk < 2; ++kk) {
      const int gk = kk * 4 + (lane >> 4);
      bf16x8 av[4], bv[4];
#pragma unroll
      for (int mi = 0; mi < 4; ++mi) {
        const int r = wr * 64 + mi * 16 + (lane & 15);
        av[mi] = *(const bf16x8*)(ldsA + r * 128 + ((gk ^ (r & 7)) << 4));
      }
#pragma unroll
      for (int ni = 0; ni < 4; ++ni) {
        const int r = wc * 64 + ni * 16 + (lane & 15);
        bv[ni] = *(const bf16x8*)(ldsB + r * 128 + ((gk ^ (r & 7)) << 4));
      }
#pragma unroll
      for (int mi = 0; mi < 4; ++mi)
#pragma unroll
        for (int ni = 0; ni < 4; ++ni)
          acc[mi][ni] = __builtin_amdgcn_mfma_f32_16x16x32_bf16(av[mi], bv[ni], acc[mi][ni], 0, 0, 0);
    }
    __syncthreads();
  }

  const int cl = lane & 15;
  const int rg = (lane >> 4) << 2;
#pragma unroll
  for (int mi = 0; mi < 4; ++mi) {
#pragma unroll
    for (int ni = 0; ni < 4; ++ni) {
      const int gr = m0 + wr * 64 + mi * 16 + rg;
      const int gc = n0 + wc * 64 + ni * 16 + cl;
      float v0 = acc[mi][ni][0], v1 = acc[mi][ni][1];
      float v2 = acc[mi][ni][2], v3 = acc[mi][ni][3];
      if (Qadd) {
        v0 += bf2f(Qadd[(size_t)(gr + 0) * 512 + gc]);
        v1 += bf2f(Qadd[(size_t)(gr + 1) * 512 + gc]);
        v2 += bf2f(Qadd[(size_t)(gr + 2) * 512 + gc]);
        v3 += bf2f(Qadd[(size_t)(gr + 3) * 512 + gc]);
      }
      unsigned short h0 = f2bf(v0), h1 = f2bf(v1), h2 = f2bf(v2), h3 = f2bf(v3);
      if (Crm) {
        Crm[(size_t)(gr + 0) * 512 + gc] = h0;
        Crm[(size_t)(gr + 1) * 512 + gc] = h1;
        Crm[(size_t)(gr + 2) * 512 + gc] = h2;
        Crm[(size_t)(gr + 3) * 512 + gc] = h3;
      }
      if (Ct) {
        us4 tvec;
        tvec[0] = h0; tvec[1] = h1; tvec[2] = h2; tvec[3] = h3;
        *(us4*)(Ct + (size_t)gc * 512 + gr) = tvec;
      }
    }
  }
}

// ---------------------------------------------------------------------------
// S[b] = Cmat[b] @ Bmat[b]^T  (per graph, 512x512x256, fp32)
// 64x64 tiles -> grid (64,8) = 512 blocks.
// ---------------------------------------------------------------------------
__global__ __launch_bounds__(256) void gemm_nt_kernel(const float* __restrict__ Cm,
                                                      const float* __restrict__ Bm,
                                                      float* __restrict__ S) {
  const int b = blockIdx.y;
  const float* Ab = Cm + (size_t)b * LNODE * DSTATE;
  const float* Bb = Bm + (size_t)b * LNODE * DSTATE;
  float* Sb = S + ((size_t)b << 18);
  const int tile = blockIdx.x;
  const int m0 = (tile >> 3) << 6;
  const int n0 = (tile & 7) << 6;
  __shared__ float As[16][68];
  __shared__ float Bs[16][68];
  const int tid = threadIdx.x;
  const int tx = tid & 15, ty = tid >> 4;
  const int srow = tid >> 2, skq = tid & 3;
  float acc[4][4] = {};
  for (int k0 = 0; k0 < DSTATE; k0 += 16) {
    float4 a = *(const float4*)(Ab + (size_t)(m0 + srow) * DSTATE + k0 + skq * 4);
    As[skq * 4 + 0][srow] = a.x; As[skq * 4 + 1][srow] = a.y;
    As[skq * 4 + 2][srow] = a.z; As[skq * 4 + 3][srow] = a.w;
    float4 c = *(const float4*)(Bb + (size_t)(n0 + srow) * DSTATE + k0 + skq * 4);
    Bs[skq * 4 + 0][srow] = c.x; Bs[skq * 4 + 1][srow] = c.y;
    Bs[skq * 4 + 2][srow] = c.z; Bs[skq * 4 + 3][srow] = c.w;
    __syncthreads();
#pragma unroll
    for (int k = 0; k < 16; ++k) {
      float av[4], bv[4];
      *(float4*)(av) = *(const float4*)(&As[k][ty * 4]);
      *(float4*)(bv) = *(const float4*)(&Bs[k][tx * 4]);
#pragma unroll
      for (int i = 0; i < 4; ++i)
#pragma unroll
        for (int j = 0; j < 4; ++j)
          acc[i][j] = fmaf(av[i], bv[j], acc[i][j]);
    }
    __syncthreads();
  }
#pragma unroll
  for (int i = 0; i < 4; ++i) {
    float* sp = Sb + (size_t)(m0 + ty * 4 + i) * 512 + n0 + tx * 4;
    *(float4*)sp = make_float4(acc[i][0], acc[i][1], acc[i][2], acc[i][3]);
  }
}

// ---------------------------------------------------------------------------
// Fused make_M + final GEMM, K-split 4-way (atomicAdd into zeroed out):
// out[(b*512+l)*256 + h*4 + n] +=
//   sum_{t in kg} (bf2f(Lm[bn][l][t]) * dts[t] * S[b][l][t]) * x[t][n*64+h]
//   (+ x[l][n*64+h]*D[n] from kg==0)
// ---------------------------------------------------------------------------
__global__ __launch_bounds__(256) void final_fused_kernel(
    const unsigned short* __restrict__ Lm, const float* __restrict__ S,
    const float* __restrict__ dt, const float* __restrict__ x,
    const float* __restrict__ Dv, float* __restrict__ out) {
  const int bn = blockIdx.z;
  const int kg = blockIdx.y;
  const int n = bn & 3, b = bn >> 2;
  const unsigned short* Lb = Lm + ((size_t)bn << 18);
  const float* Sb = S + ((size_t)b << 18);
  const float* xb = x + (size_t)b * LNODE * DINNER + n * HEADD;
  const int m0 = blockIdx.x << 7;
  const int kbase = kg << 7;
  __shared__ float Ms[16][132];
  __shared__ float Xs[16][64];
  __shared__ float dts_all[128];
  const int tid = threadIdx.x;
  const int tx = tid & 15, ty = tid >> 4;
  if (tid < 128)
    dts_all[tid] = dt[(size_t)(b * 512 + kbase + tid) * 16 + n * 4 + 3];
  __syncthreads();
  float acc[8][4] = {};
  for (int kk0 = 0; kk0 < 128; kk0 += 16) {
    const int k0 = kbase + kk0;
#pragma unroll
    for (int s = 0; s < 2; ++s) {
      int fid = tid + s * 256;
      int m = fid >> 2, kq = fid & 3;
      us4 lm = *(const us4*)(Lb + (size_t)(m0 + m) * 512 + k0 + kq * 4);
      float4 sv = *(const float4*)(Sb + (size_t)(m0 + m) * 512 + k0 + kq * 4);
      Ms[kq * 4 + 0][m] = bf2f(lm[0]) * sv.x * dts_all[kk0 + kq * 4 + 0];
      Ms[kq * 4 + 1][m] = bf2f(lm[1]) * sv.y * dts_all[kk0 + kq * 4 + 1];
      Ms[kq * 4 + 2][m] = bf2f(lm[2]) * sv.z * dts_all[kk0 + kq * 4 + 2];
      Ms[kq * 4 + 3][m] = bf2f(lm[3]) * sv.w * dts_all[kk0 + kq * 4 + 3];
    }
    {
      int kk = tid >> 4, hq = tid & 15;
      float4 v = *(const float4*)(xb + (size_t)(k0 + kk) * DINNER + hq * 4);
      *(float4*)(&Xs[kk][hq * 4]) = v;
    }
    __syncthreads();
#pragma unroll
    for (int k = 0; k < 16; ++k) {
      float mv[8], xv[4];
      *(float4*)(mv)     = *(const float4*)(&Ms[k][ty * 8]);
      *(float4*)(mv + 4) = *(const float4*)(&Ms[k][ty * 8 + 4]);
      *(float4*)(xv)     = *(const float4*)(&Xs[k][tx * 4]);
#pragma unroll
      for (int i = 0; i < 8; ++i)
#pragma unroll
        for (int j = 0; j < 4; ++j)
          acc[i][j] = fmaf(mv[i], xv[j], acc[i][j]);
    }
    __syncthreads();
  }
  const float Dn = Dv[n];
#pragma unroll
  for (int i = 0; i < 8; ++i) {
    const int l = m0 + ty * 8 + i;
    const float* xrow = x + (size_t)(b * LNODE + l) * DINNER + n * HEADD;
    float* orow = out + (size_t)(b * LNODE + l) * DINNER + n;
#pragma unroll
    for (int j = 0; j < 4; ++j) {
      const int h = tx * 4 + j;
      float v = acc[i][j];
      if (kg == 0) v += xrow[h] * Dn;
      atomicAdd(&orow[h * 4], v);
    }
  }
}

// ---------------------------------------------------------------------------
extern "C" void kernel_launch(void* const* d_in, const int* in_sizes, int n_in,
                              void* d_out, int out_size, void* d_ws, size_t ws_size,
                              hipStream_t stream) {
  const float* x        = (const float*)d_in[0];
  const float* Bmat     = (const float*)d_in[1];
  const float* Cmat     = (const float*)d_in[2];
  const float* dt       = (const float*)d_in[3];
  const float* dt_edge  = (const float*)d_in[4];
  const float* dt_bias  = (const float*)d_in[5];
  const float* Dv       = (const float*)d_in[6];
  const int* edge_index = (const int*)d_in[7];
  float* out = (float*)d_out;

  // Workspace: 6 rotating bf16 slots of 16.78 MB + colsum. Peak 96.1 MB.
  //  slotD+slotE initially hold G (fp32, 32 MB); Sbuf reuses slotF after L3.
  char* wsb = (char*)d_ws;
  const size_t SL = 16777216;
  unsigned short* sA = (unsigned short*)(wsb + 0 * SL);
  unsigned short* sB = (unsigned short*)(wsb + 1 * SL);
  unsigned short* sC = (unsigned short*)(wsb + 2 * SL);
  unsigned short* sD = (unsigned short*)(wsb + 3 * SL);
  unsigned short* sE = (unsigned short*)(wsb + 4 * SL);
  unsigned short* sF = (unsigned short*)(wsb + 5 * SL);
  float* G      = (float*)(wsb + 3 * SL);   // 32 MB fp32, dead after conv
  float* Sbuf   = (float*)(wsb + 5 * SL);   // 8.4 MB fp32, written after L3
  float* colsum = (float*)(wsb + 6 * SL);   // 64 KB

  hipMemsetAsync(G, 0, 33554432, stream);
  hipMemsetAsync(colsum, 0, 32 * 512 * 4, stream);
  hipMemsetAsync(out, 0, (size_t)out_size * 4, stream);
  scatter_edges_kernel<<<1024, 256, 0, stream>>>(dt, dt_edge, dt_bias, edge_index, G, colsum);
  // conv: A=Prm, B=Pt, C=Q0
  conv_kernel<<<dim3(256, 32), 256, 0, stream>>>(G, colsum, dt, dt_bias, sA, sB, sC);

  // Doubling chain, restructured so each stage's two GEMMs are independent:
  //   F1=P@P; F2=F1@F1 || U0=Q0@F1t+Q0; F3=F2@F2 || U1=U0@F2t+U0;
  //   F4=F3@F3 (t only) || U2=U1@F3t+U1; U3=U2@F4t+U2  (= Lm)
  dim3 g1(16, 32, 1), g2(16, 32, 2);
  // L1: F1(rm->D, t->E) = P@P
  gemm_pair_kernel<<<g1, 256, 0, stream>>>(sA, sB, sD, sE, nullptr,
                                           nullptr, nullptr, nullptr, nullptr, nullptr);
  // L2: F2(rm->A,t->B)=F1@F1  ||  U0(->F)=Q0@F1t+Q0
  gemm_pair_kernel<<<g2, 256, 0, stream>>>(sD, sE, sA, sB, nullptr,
                                           sC, sE, sF, nullptr, sC);
  // L3: F3(rm->C,t->D)=F2@F2  ||  U1(->E)=U0@F2t+U0
  gemm_pair_kernel<<<g2, 256, 0, stream>>>(sA, sB, sC, sD, nullptr,
                                           sF, sB, sE, nullptr, sF);
  // S = Cmat@Bmat^T into slotF (U0 dead after L3)
  gemm_nt_kernel<<<dim3(64, 8), 256, 0, stream>>>(Cmat, Bmat, Sbuf);
  // L4: F4(t->A)=F3@F3  ||  U2(->B)=U1@F3t+U1
  gemm_pair_kernel<<<g2, 256, 0, stream>>>(sC, sD, nullptr, sA, nullptr,
                                           sE, sD, sB, nullptr, sE);
  // L5: U3(->C)=U2@F4t+U2   (= Lm)
  gemm_pair_kernel<<<g1, 256, 0, stream>>>(sB, sA, sC, nullptr, sB,
                                           nullptr, nullptr, nullptr, nullptr, nullptr);

  final_fused_kernel<<<dim3(4, 4, 32), 256, 0, stream>>>(sC, Sbuf, dt, x, Dv, out);
}

// Round 5
// 290.161 us; speedup vs baseline: 1.7245x; 1.7245x over previous
//
#include <hip/hip_runtime.h>
#include <math.h>

#define N_EDGES 65536
#define LNODE 512
#define DSTATE 256
#define DINNER 256
#define HEADD 64

using bf16x8 = __attribute__((ext_vector_type(8))) short;
using f32x4  = __attribute__((ext_vector_type(4))) float;
using us4    = __attribute__((ext_vector_type(4))) unsigned short;

__device__ __forceinline__ float softplusf(float z) {
  return (z > 0.0f) ? (z + log1pf(expf(-z))) : log1pf(expf(z));
}
__device__ __forceinline__ float bf2f(unsigned short u) {
  unsigned int x = ((unsigned int)u) << 16;
  return __builtin_bit_cast(float, x);
}
__device__ __forceinline__ unsigned short f2bf(float f) {
  unsigned int x = __builtin_bit_cast(unsigned int, f);
  x += 0x7fffu + ((x >> 16) & 1u);
  return (unsigned short)(x >> 16);
}

// ---------------------------------------------------------------------------
// Scatter edges into G = A^T (per (graph,head) 512x512), G[l2][l1] += val,
// plus column sums colsum[bn][l1] += val.
// ---------------------------------------------------------------------------
__global__ void scatter_edges_kernel(const float* __restrict__ dt,
                                     const float* __restrict__ dt_edge,
                                     const float* __restrict__ dt_bias,
                                     const int* __restrict__ edge_index,
                                     float* __restrict__ G,
                                     float* __restrict__ colsum) {
  int t = blockIdx.x * blockDim.x + threadIdx.x;
  if (t >= N_EDGES * 4) return;
  int e = t >> 2;
  int n = t & 3;
  int src = edge_index[e];
  int dst = edge_index[N_EDGES + e];
  float bias = dt_bias[n];
  float z0 = dt[src * 16 + n * 4 + 0] + bias;
  float z1 = dt[dst * 16 + n * 4 + 1] + bias;
  float z2 = dt_edge[e * 4 + n] + bias;
  float val = expf(-(softplusf(z0) + softplusf(z1) + softplusf(z2)) * (1.0f / 3.0f));
  int b = src >> 9;
  int l1 = src & 511;
  int l2 = dst & 511;
  int bn = b * 4 + n;
  atomicAdd(&G[(((size_t)bn) << 18) + ((size_t)l2 << 9) + l1], val);
  atomicAdd(&colsum[bn * 512 + l1], val);
}

// ---------------------------------------------------------------------------
// Convert + normalize: v = G * inv(col); Prm = bf16(v), Pt = bf16(v^T),
// Q = bf16(I + v). 32x32 tiles.
// ---------------------------------------------------------------------------
__global__ __launch_bounds__(256) void conv_kernel(const float* __restrict__ G,
                                                   const float* __restrict__ colsum,
                                                   const float* __restrict__ dt,
                                                   const float* __restrict__ dt_bias,
                                                   unsigned short* __restrict__ Prm,
                                                   unsigned short* __restrict__ Pt,
                                                   unsigned short* __restrict__ Q) {
  const int bn = blockIdx.y;
  const int n = bn & 3, b = bn >> 2;
  const size_t base = (size_t)bn << 18;
  const int tile = blockIdx.x;
  const int ro = (tile >> 4) << 5;
  const int co = (tile & 15) << 5;
  __shared__ float lds[32][33];
  __shared__ float sinv[32];
  const int t = threadIdx.x;
  if (t < 32) {
    const int col = co + t;
    float ssum = colsum[bn * 512 + col];
    float bias = dt_bias[n];
    float dummy = expf(-softplusf(dt[(size_t)(b * 512 + col) * 16 + n * 4 + 2] + bias));
    float norm = fmaxf(1.0f, ssum + dummy);
    sinv[t] = 1.0f / (norm + 0.05f);
  }
  __syncthreads();
  const int tr = t >> 3;
  const int tc0 = (t & 7) << 2;
  float4 gv = *(const float4*)(G + base + (size_t)(ro + tr) * 512 + co + tc0);
  float vv[4] = {gv.x, gv.y, gv.z, gv.w};
  us4 p, q;
#pragma unroll
  for (int j = 0; j < 4; ++j) {
    vv[j] *= sinv[tc0 + j];
    p[j] = f2bf(vv[j]);
    float qq = vv[j] + (((ro + tr) == (co + tc0 + j)) ? 1.0f : 0.0f);
    q[j] = f2bf(qq);
    lds[tc0 + j][tr] = vv[j];
  }
  *(us4*)(Prm + base + (size_t)(ro + tr) * 512 + co + tc0) = p;
  *(us4*)(Q + base + (size_t)(ro + tr) * 512 + co + tc0) = q;
  __syncthreads();
  us4 pt;
#pragma unroll
  for (int j = 0; j < 4; ++j) pt[j] = f2bf(lds[tr][tc0 + j]);
  *(us4*)(Pt + base + (size_t)(co + tr) * 512 + ro + tc0) = pt;
}

// ---------------------------------------------------------------------------
// Paired batched bf16 MFMA GEMM: z = blockIdx.z selects operand set.
// C = A @ B (+ Qadd if non-null), B given transposed ([N][K]).
// Writes Crm (row-major) and/or Ct (transposed) if non-null.
// 128x128 tile, BK=64, 4 waves, global_load_lds, XOR-swizzled LDS.
// ---------------------------------------------------------------------------
__global__ __launch_bounds__(256) void gemm_pair_kernel(
    const unsigned short* __restrict__ A0, const unsigned short* __restrict__ B0,
    unsigned short* __restrict__ C0rm, unsigned short* __restrict__ C0t,
    const unsigned short* __restrict__ Q0,
    const unsigned short* __restrict__ A1, const unsigned short* __restrict__ B1,
    unsigned short* __restrict__ C1rm, unsigned short* __restrict__ C1t,
    const unsigned short* __restrict__ Q1) {
  const int z = blockIdx.z;
  const unsigned short* A    = z ? A1 : A0;
  const unsigned short* Bt   = z ? B1 : B0;
  unsigned short* Crm        = z ? C1rm : C0rm;
  unsigned short* Ct         = z ? C1t : C0t;
  const unsigned short* Qadd = z ? Q1 : Q0;

  const int bn = blockIdx.y;
  const size_t off = (size_t)bn << 18;
  A += off; Bt += off;
  if (Crm) Crm += off;
  if (Ct) Ct += off;
  if (Qadd) Qadd += off;
  const int m0 = (blockIdx.x >> 2) << 7;
  const int n0 = (blockIdx.x & 3) << 7;
  __shared__ __align__(16) char lds[32768];
  char* ldsA = lds;
  char* ldsB = lds + 16384;
  const int tid = threadIdx.x;
  const int lane = tid & 63;
  const int w = tid >> 6;
  const int wr = w >> 1, wc = w & 1;
  const int lr = lane >> 3, g = lane & 7;

  f32x4 acc[4][4];
#pragma unroll
  for (int i = 0; i < 4; ++i)
#pragma unroll
    for (int j = 0; j < 4; ++j) acc[i][j] = (f32x4)(0.0f);

  for (int k0 = 0; k0 < 512; k0 += 64) {
#pragma unroll
    for (int s = 0; s < 4; ++s) {
      const int r = s * 32 + w * 8 + lr;
      const unsigned short* ga = A + (size_t)(m0 + r) * 512 + k0 + ((g ^ (r & 7)) << 3);
      __builtin_amdgcn_global_load_lds(
          (const __attribute__((address_space(1))) void*)ga,
          (__attribute__((address_space(3))) void*)(ldsA + s * 4096 + w * 1024 + (lane << 4)),
          16, 0, 0);
      const unsigned short* gb = Bt + (size_t)(n0 + r) * 512 + k0 + ((g ^ (r & 7)) << 3);
      __builtin_amdgcn_global_load_lds(
          (const __attribute__((address_space(1))) void*)gb,
          (__attribute__((address_space(3))) void*)(ldsB + s * 4096 + w * 1024 + (lane << 4)),
          16, 0, 0);
    }
    __syncthreads();
#pragma unroll
    for (int kk = 0; kk < 2; ++kk) {
      const int gk = kk * 4 + (lane >> 4);
      bf16x8 av[4], bv[4];
#pragma unroll
      for (int mi = 0; mi < 4; ++mi) {
        const int r = wr * 64 + mi * 16 + (lane & 15);
        av[mi] = *(const bf16x8*)(ldsA + r * 128 + ((gk ^ (r & 7)) << 4));
      }
#pragma unroll
      for (int ni = 0; ni < 4; ++ni) {
        const int r = wc * 64 + ni * 16 + (lane & 15);
        bv[ni] = *(const bf16x8*)(ldsB + r * 128 + ((gk ^ (r & 7)) << 4));
      }
#pragma unroll
      for (int mi = 0; mi < 4; ++mi)
#pragma unroll
        for (int ni = 0; ni < 4; ++ni)
          acc[mi][ni] = __builtin_amdgcn_mfma_f32_16x16x32_bf16(av[mi], bv[ni], acc[mi][ni], 0, 0, 0);
    }
    __syncthreads();
  }

  const int cl = lane & 15;
  const int rg = (lane >> 4) << 2;
#pragma unroll
  for (int mi = 0; mi < 4; ++mi) {
#pragma unroll
    for (int ni = 0; ni < 4; ++ni) {
      const int gr = m0 + wr * 64 + mi * 16 + rg;
      const int gc = n0 + wc * 64 + ni * 16 + cl;
      float v0 = acc[mi][ni][0], v1 = acc[mi][ni][1];
      float v2 = acc[mi][ni][2], v3 = acc[mi][ni][3];
      if (Qadd) {
        v0 += bf2f(Qadd[(size_t)(gr + 0) * 512 + gc]);
        v1 += bf2f(Qadd[(size_t)(gr + 1) * 512 + gc]);
        v2 += bf2f(Qadd[(size_t)(gr + 2) * 512 + gc]);
        v3 += bf2f(Qadd[(size_t)(gr + 3) * 512 + gc]);
      }
      unsigned short h0 = f2bf(v0), h1 = f2bf(v1), h2 = f2bf(v2), h3 = f2bf(v3);
      if (Crm) {
        Crm[(size_t)(gr + 0) * 512 + gc] = h0;
        Crm[(size_t)(gr + 1) * 512 + gc] = h1;
        Crm[(size_t)(gr + 2) * 512 + gc] = h2;
        Crm[(size_t)(gr + 3) * 512 + gc] = h3;
      }
      if (Ct) {
        us4 tvec;
        tvec[0] = h0; tvec[1] = h1; tvec[2] = h2; tvec[3] = h3;
        *(us4*)(Ct + (size_t)gc * 512 + gr) = tvec;
      }
    }
  }
}

// ---------------------------------------------------------------------------
// S[b] = Cmat[b] @ Bmat[b]^T  (per graph, 512x512x256, fp32)
// 64x64 tiles -> grid (64,8) = 512 blocks.
// ---------------------------------------------------------------------------
__global__ __launch_bounds__(256) void gemm_nt_kernel(const float* __restrict__ Cm,
                                                      const float* __restrict__ Bm,
                                                      float* __restrict__ S) {
  const int b = blockIdx.y;
  const float* Ab = Cm + (size_t)b * LNODE * DSTATE;
  const float* Bb = Bm + (size_t)b * LNODE * DSTATE;
  float* Sb = S + ((size_t)b << 18);
  const int tile = blockIdx.x;
  const int m0 = (tile >> 3) << 6;
  const int n0 = (tile & 7) << 6;
  __shared__ float As[16][68];
  __shared__ float Bs[16][68];
  const int tid = threadIdx.x;
  const int tx = tid & 15, ty = tid >> 4;
  const int srow = tid >> 2, skq = tid & 3;
  float acc[4][4] = {};
  for (int k0 = 0; k0 < DSTATE; k0 += 16) {
    float4 a = *(const float4*)(Ab + (size_t)(m0 + srow) * DSTATE + k0 + skq * 4);
    As[skq * 4 + 0][srow] = a.x; As[skq * 4 + 1][srow] = a.y;
    As[skq * 4 + 2][srow] = a.z; As[skq * 4 + 3][srow] = a.w;
    float4 c = *(const float4*)(Bb + (size_t)(n0 + srow) * DSTATE + k0 + skq * 4);
    Bs[skq * 4 + 0][srow] = c.x; Bs[skq * 4 + 1][srow] = c.y;
    Bs[skq * 4 + 2][srow] = c.z; Bs[skq * 4 + 3][srow] = c.w;
    __syncthreads();
#pragma unroll
    for (int k = 0; k < 16; ++k) {
      float av[4], bv[4];
      *(float4*)(av) = *(const float4*)(&As[k][ty * 4]);
      *(float4*)(bv) = *(const float4*)(&Bs[k][tx * 4]);
#pragma unroll
      for (int i = 0; i < 4; ++i)
#pragma unroll
        for (int j = 0; j < 4; ++j)
          acc[i][j] = fmaf(av[i], bv[j], acc[i][j]);
    }
    __syncthreads();
  }
#pragma unroll
  for (int i = 0; i < 4; ++i) {
    float* sp = Sb + (size_t)(m0 + ty * 4 + i) * 512 + n0 + tx * 4;
    *(float4*)sp = make_float4(acc[i][0], acc[i][1], acc[i][2], acc[i][3]);
  }
}

// ---------------------------------------------------------------------------
// Fused make_M + final GEMM, K-split 4-way into PRIVATE partial buffers
// (no atomics): P[kg][bn][l][h] = sum_{t in kg} M[bn][l][t] * x[t][n*64+h]
// ---------------------------------------------------------------------------
__global__ __launch_bounds__(256) void final_fused_kernel(
    const unsigned short* __restrict__ Lm, const float* __restrict__ S,
    const float* __restrict__ dt, const float* __restrict__ x,
    float* __restrict__ P) {
  const int bn = blockIdx.z;
  const int kg = blockIdx.y;
  const int n = bn & 3, b = bn >> 2;
  const unsigned short* Lb = Lm + ((size_t)bn << 18);
  const float* Sb = S + ((size_t)b << 18);
  const float* xb = x + (size_t)b * LNODE * DINNER + n * HEADD;
  const int m0 = blockIdx.x << 7;
  const int kbase = kg << 7;
  __shared__ float Ms[16][132];
  __shared__ float Xs[16][64];
  __shared__ float dts_all[128];
  const int tid = threadIdx.x;
  const int tx = tid & 15, ty = tid >> 4;
  if (tid < 128)
    dts_all[tid] = dt[(size_t)(b * 512 + kbase + tid) * 16 + n * 4 + 3];
  __syncthreads();
  float acc[8][4] = {};
  for (int kk0 = 0; kk0 < 128; kk0 += 16) {
    const int k0 = kbase + kk0;
#pragma unroll
    for (int s = 0; s < 2; ++s) {
      int fid = tid + s * 256;
      int m = fid >> 2, kq = fid & 3;
      us4 lm = *(const us4*)(Lb + (size_t)(m0 + m) * 512 + k0 + kq * 4);
      float4 sv = *(const float4*)(Sb + (size_t)(m0 + m) * 512 + k0 + kq * 4);
      Ms[kq * 4 + 0][m] = bf2f(lm[0]) * sv.x * dts_all[kk0 + kq * 4 + 0];
      Ms[kq * 4 + 1][m] = bf2f(lm[1]) * sv.y * dts_all[kk0 + kq * 4 + 1];
      Ms[kq * 4 + 2][m] = bf2f(lm[2]) * sv.z * dts_all[kk0 + kq * 4 + 2];
      Ms[kq * 4 + 3][m] = bf2f(lm[3]) * sv.w * dts_all[kk0 + kq * 4 + 3];
    }
    {
      int kk = tid >> 4, hq = tid & 15;
      float4 v = *(const float4*)(xb + (size_t)(k0 + kk) * DINNER + hq * 4);
      *(float4*)(&Xs[kk][hq * 4]) = v;
    }
    __syncthreads();
#pragma unroll
    for (int k = 0; k < 16; ++k) {
      float mv[8], xv[4];
      *(float4*)(mv)     = *(const float4*)(&Ms[k][ty * 8]);
      *(float4*)(mv + 4) = *(const float4*)(&Ms[k][ty * 8 + 4]);
      *(float4*)(xv)     = *(const float4*)(&Xs[k][tx * 4]);
#pragma unroll
      for (int i = 0; i < 8; ++i)
#pragma unroll
        for (int j = 0; j < 4; ++j)
          acc[i][j] = fmaf(mv[i], xv[j], acc[i][j]);
    }
    __syncthreads();
  }
  // coalesced partial store: P[kg][bn][l][h], h = tx*4..tx*4+3
  float* Pb = P + (((size_t)(kg * 32 + bn)) << 15);
#pragma unroll
  for (int i = 0; i < 8; ++i) {
    const int l = m0 + ty * 8 + i;
    *(float4*)(Pb + (size_t)l * 64 + tx * 4) =
        make_float4(acc[i][0], acc[i][1], acc[i][2], acc[i][3]);
  }
}

// ---------------------------------------------------------------------------
// Reduce partials + D*x residual, emit h*4+n interleave (coalesced float4).
// out[(b*512+l)*256 + h*4 + n] = sum_kg P[kg][b*4+n][l][h] + x[b,l,n*64+h]*D[n]
// ---------------------------------------------------------------------------
__global__ __launch_bounds__(256) void reduce_out_kernel(
    const float* __restrict__ P, const float* __restrict__ x,
    const float* __restrict__ Dv, float* __restrict__ out) {
  int t = blockIdx.x * 256 + threadIdx.x;  // 8*512*64 = 262144
  int h = t & 63;
  int l = (t >> 6) & 511;
  int b = t >> 15;
  float4 v;
#pragma unroll
  for (int n = 0; n < 4; ++n) {
    int bn = b * 4 + n;
    float s = 0.0f;
#pragma unroll
    for (int kg = 0; kg < 4; ++kg)
      s += P[(((size_t)(kg * 32 + bn)) << 15) + (size_t)l * 64 + h];
    s += x[(size_t)(b * 512 + l) * 256 + n * 64 + h] * Dv[n];
    ((float*)&v)[n] = s;
  }
  *(float4*)(out + (size_t)(b * 512 + l) * 256 + h * 4) = v;
}

// ---------------------------------------------------------------------------
extern "C" void kernel_launch(void* const* d_in, const int* in_sizes, int n_in,
                              void* d_out, int out_size, void* d_ws, size_t ws_size,
                              hipStream_t stream) {
  const float* x        = (const float*)d_in[0];
  const float* Bmat     = (const float*)d_in[1];
  const float* Cmat     = (const float*)d_in[2];
  const float* dt       = (const float*)d_in[3];
  const float* dt_edge  = (const float*)d_in[4];
  const float* dt_bias  = (const float*)d_in[5];
  const float* Dv       = (const float*)d_in[6];
  const int* edge_index = (const int*)d_in[7];
  float* out = (float*)d_out;

  // Workspace: 6 rotating bf16 slots of 16.78 MB + colsum. Peak ~100.7 MB.
  //  slotD+slotE initially hold G (fp32); Sbuf reuses slotF after L3;
  //  partial-P reuses slotD after L4.
  char* wsb = (char*)d_ws;
  const size_t SL = 16777216;
  unsigned short* sA = (unsigned short*)(wsb + 0 * SL);
  unsigned short* sB = (unsigned short*)(wsb + 1 * SL);
  unsigned short* sC = (unsigned short*)(wsb + 2 * SL);
  unsigned short* sD = (unsigned short*)(wsb + 3 * SL);
  unsigned short* sE = (unsigned short*)(wsb + 4 * SL);
  unsigned short* sF = (unsigned short*)(wsb + 5 * SL);
  float* G      = (float*)(wsb + 3 * SL);   // 32 MB fp32, dead after conv
  float* Sbuf   = (float*)(wsb + 5 * SL);   // 8.4 MB fp32, written after L3
  float* Pbuf   = (float*)(wsb + 3 * SL);   // 16.8 MB fp32, written after L4
  float* colsum = (float*)(wsb + 6 * SL);   // 64 KB

  hipMemsetAsync(G, 0, 33554432, stream);
  hipMemsetAsync(colsum, 0, 32 * 512 * 4, stream);
  scatter_edges_kernel<<<1024, 256, 0, stream>>>(dt, dt_edge, dt_bias, edge_index, G, colsum);
  // conv: A=Prm, B=Pt, C=Q0
  conv_kernel<<<dim3(256, 32), 256, 0, stream>>>(G, colsum, dt, dt_bias, sA, sB, sC);

  // Doubling chain, paired so each stage's two GEMMs are independent:
  //   F1=P@P; F2=F1@F1 || U0=Q0@F1t+Q0; F3=F2@F2 || U1=U0@F2t+U0;
  //   F4=F3@F3 (t only) || U2=U1@F3t+U1; U3=U2@F4t+U2  (= Lm)
  dim3 g1(16, 32, 1), g2(16, 32, 2);
  // L1: F1(rm->D, t->E) = P@P
  gemm_pair_kernel<<<g1, 256, 0, stream>>>(sA, sB, sD, sE, nullptr,
                                           nullptr, nullptr, nullptr, nullptr, nullptr);
  // L2: F2(rm->A,t->B)=F1@F1  ||  U0(->F)=Q0@F1t+Q0
  gemm_pair_kernel<<<g2, 256, 0, stream>>>(sD, sE, sA, sB, nullptr,
                                           sC, sE, sF, nullptr, sC);
  // L3: F3(rm->C,t->D)=F2@F2  ||  U1(->E)=U0@F2t+U0
  gemm_pair_kernel<<<g2, 256, 0, stream>>>(sA, sB, sC, sD, nullptr,
                                           sF, sB, sE, nullptr, sF);
  // S = Cmat@Bmat^T into slotF (U0 dead after L3)
  gemm_nt_kernel<<<dim3(64, 8), 256, 0, stream>>>(Cmat, Bmat, Sbuf);
  // L4: F4(t->A)=F3@F3  ||  U2(->B)=U1@F3t+U1
  gemm_pair_kernel<<<g2, 256, 0, stream>>>(sC, sD, nullptr, sA, nullptr,
                                           sE, sD, sB, nullptr, sE);
  // L5: U3(->C)=U2@F4t+U2   (= Lm)
  gemm_pair_kernel<<<g1, 256, 0, stream>>>(sB, sA, sC, nullptr, sB,
                                           nullptr, nullptr, nullptr, nullptr, nullptr);

  // Final: K-split partials (slotD) then reduce+interleave.
  final_fused_kernel<<<dim3(4, 4, 32), 256, 0, stream>>>(sC, Sbuf, dt, x, Pbuf);
  reduce_out_kernel<<<1024, 256, 0, stream>>>(Pbuf, x, Dv, out);
}

// Round 6
// 225.881 us; speedup vs baseline: 2.2153x; 1.2846x over previous
//
#include <hip/hip_runtime.h>
#include <math.h>

#define N_EDGES 65536
#define LNODE 512
#define DSTATE 256
#define DINNER 256
#define HEADD 64

using bf16x8 = __attribute__((ext_vector_type(8))) short;
using f32x4  = __attribute__((ext_vector_type(4))) float;
using us4    = __attribute__((ext_vector_type(4))) unsigned short;

__device__ __forceinline__ float softplusf(float z) {
  return (z > 0.0f) ? (z + log1pf(expf(-z))) : log1pf(expf(z));
}
__device__ __forceinline__ float bf2f(unsigned short u) {
  unsigned int x = ((unsigned int)u) << 16;
  return __builtin_bit_cast(float, x);
}
__device__ __forceinline__ unsigned short f2bf(float f) {
  unsigned int x = __builtin_bit_cast(unsigned int, f);
  x += 0x7fffu + ((x >> 16) & 1u);
  return (unsigned short)(x >> 16);
}

// ---------------------------------------------------------------------------
// Scatter edges into G = A^T (per (graph,head) 512x512), G[l2][l1] += val,
// plus column sums colsum[bn][l1] += val.
// ---------------------------------------------------------------------------
__global__ void scatter_edges_kernel(const float* __restrict__ dt,
                                     const float* __restrict__ dt_edge,
                                     const float* __restrict__ dt_bias,
                                     const int* __restrict__ edge_index,
                                     float* __restrict__ G,
                                     float* __restrict__ colsum) {
  int t = blockIdx.x * blockDim.x + threadIdx.x;
  if (t >= N_EDGES * 4) return;
  int e = t >> 2;
  int n = t & 3;
  int src = edge_index[e];
  int dst = edge_index[N_EDGES + e];
  float bias = dt_bias[n];
  float z0 = dt[src * 16 + n * 4 + 0] + bias;
  float z1 = dt[dst * 16 + n * 4 + 1] + bias;
  float z2 = dt_edge[e * 4 + n] + bias;
  float val = expf(-(softplusf(z0) + softplusf(z1) + softplusf(z2)) * (1.0f / 3.0f));
  int b = src >> 9;
  int l1 = src & 511;
  int l2 = dst & 511;
  int bn = b * 4 + n;
  atomicAdd(&G[(((size_t)bn) << 18) + ((size_t)l2 << 9) + l1], val);
  atomicAdd(&colsum[bn * 512 + l1], val);
}

// ---------------------------------------------------------------------------
// Convert + normalize: v = G * inv(col); Prm = bf16(v), Pt = bf16(v^T),
// Q = bf16(I + v). 32x32 tiles.
// ---------------------------------------------------------------------------
__global__ __launch_bounds__(256) void conv_kernel(const float* __restrict__ G,
                                                   const float* __restrict__ colsum,
                                                   const float* __restrict__ dt,
                                                   const float* __restrict__ dt_bias,
                                                   unsigned short* __restrict__ Prm,
                                                   unsigned short* __restrict__ Pt,
                                                   unsigned short* __restrict__ Q) {
  const int bn = blockIdx.y;
  const int n = bn & 3, b = bn >> 2;
  const size_t base = (size_t)bn << 18;
  const int tile = blockIdx.x;
  const int ro = (tile >> 4) << 5;
  const int co = (tile & 15) << 5;
  __shared__ float lds[32][33];
  __shared__ float sinv[32];
  const int t = threadIdx.x;
  if (t < 32) {
    const int col = co + t;
    float ssum = colsum[bn * 512 + col];
    float bias = dt_bias[n];
    float dummy = expf(-softplusf(dt[(size_t)(b * 512 + col) * 16 + n * 4 + 2] + bias));
    float norm = fmaxf(1.0f, ssum + dummy);
    sinv[t] = 1.0f / (norm + 0.05f);
  }
  __syncthreads();
  const int tr = t >> 3;
  const int tc0 = (t & 7) << 2;
  float4 gv = *(const float4*)(G + base + (size_t)(ro + tr) * 512 + co + tc0);
  float vv[4] = {gv.x, gv.y, gv.z, gv.w};
  us4 p, q;
#pragma unroll
  for (int j = 0; j < 4; ++j) {
    vv[j] *= sinv[tc0 + j];
    p[j] = f2bf(vv[j]);
    float qq = vv[j] + (((ro + tr) == (co + tc0 + j)) ? 1.0f : 0.0f);
    q[j] = f2bf(qq);
    lds[tc0 + j][tr] = vv[j];
  }
  *(us4*)(Prm + base + (size_t)(ro + tr) * 512 + co + tc0) = p;
  *(us4*)(Q + base + (size_t)(ro + tr) * 512 + co + tc0) = q;
  __syncthreads();
  us4 pt;
#pragma unroll
  for (int j = 0; j < 4; ++j) pt[j] = f2bf(lds[tr][tc0 + j]);
  *(us4*)(Pt + base + (size_t)(co + tr) * 512 + ro + tc0) = pt;
}

// ---------------------------------------------------------------------------
// Paired batched bf16 MFMA GEMM, double-buffered LDS + XCD-locality swizzle.
// C = A @ B (+ Qadd if non-null), B given transposed ([N][K]).
// Writes Crm and/or Ct if non-null. 128x128 tile, BK=64, 4 waves.
// Workgroup decode: all 16 tiles of one (bn,z) unit share id%8 -> same XCD L2.
// ---------------------------------------------------------------------------
__global__ __launch_bounds__(256) void gemm_pair_kernel(
    const unsigned short* __restrict__ A0, const unsigned short* __restrict__ B0,
    unsigned short* __restrict__ C0rm, unsigned short* __restrict__ C0t,
    const unsigned short* __restrict__ Q0,
    const unsigned short* __restrict__ A1, const unsigned short* __restrict__ B1,
    unsigned short* __restrict__ C1rm, unsigned short* __restrict__ C1t,
    const unsigned short* __restrict__ Q1) {
  // bijective swizzle: f = ((kk>>3)*16 + tile)*8 + (kk&7), kk = z*32 + bn
  const int f = (blockIdx.z * gridDim.y + blockIdx.y) * gridDim.x + blockIdx.x;
  const int rres = f & 7;
  const int q = f >> 3;
  const int tile = q & 15;
  const int kk_ = ((q >> 4) << 3) + rres;
  const int bn = kk_ & 31;
  const int z = kk_ >> 5;

  const unsigned short* A    = z ? A1 : A0;
  const unsigned short* Bt   = z ? B1 : B0;
  unsigned short* Crm        = z ? C1rm : C0rm;
  unsigned short* Ct         = z ? C1t : C0t;
  const unsigned short* Qadd = z ? Q1 : Q0;

  const size_t off = (size_t)bn << 18;
  A += off; Bt += off;
  if (Crm) Crm += off;
  if (Ct) Ct += off;
  if (Qadd) Qadd += off;
  const int m0 = (tile >> 2) << 7;
  const int n0 = (tile & 3) << 7;
  __shared__ __align__(16) char lds[65536];   // 2 x (16KB A + 16KB B)
  const int tid = threadIdx.x;
  const int lane = tid & 63;
  const int w = tid >> 6;
  const int wr = w >> 1, wc = w & 1;
  const int lr = lane >> 3, g = lane & 7;

  f32x4 acc[4][4];
#pragma unroll
  for (int i = 0; i < 4; ++i)
#pragma unroll
    for (int j = 0; j < 4; ++j) acc[i][j] = (f32x4)(0.0f);

  // stage tile at k0 into buffer buf (0/1)
  auto stage = [&](int buf, int k0) {
    char* la = lds + buf * 32768;
    char* lb = la + 16384;
#pragma unroll
    for (int s = 0; s < 4; ++s) {
      const int r = s * 32 + w * 8 + lr;
      const unsigned short* ga = A + (size_t)(m0 + r) * 512 + k0 + ((g ^ (r & 7)) << 3);
      __builtin_amdgcn_global_load_lds(
          (const __attribute__((address_space(1))) void*)ga,
          (__attribute__((address_space(3))) void*)(la + s * 4096 + w * 1024 + (lane << 4)),
          16, 0, 0);
      const unsigned short* gb = Bt + (size_t)(n0 + r) * 512 + k0 + ((g ^ (r & 7)) << 3);
      __builtin_amdgcn_global_load_lds(
          (const __attribute__((address_space(1))) void*)gb,
          (__attribute__((address_space(3))) void*)(lb + s * 4096 + w * 1024 + (lane << 4)),
          16, 0, 0);
    }
  };

  stage(0, 0);
  __syncthreads();            // drain prologue loads (vmcnt0) + barrier

  for (int t = 0; t < 8; ++t) {
    const int cur = t & 1;
    if (t < 7) stage(cur ^ 1, (t + 1) * 64);   // issue next tile FIRST
    char* la = lds + cur * 32768;
    char* lb = la + 16384;
#pragma unroll
    for (int kk = 0; kk < 2; ++kk) {
      const int gk = kk * 4 + (lane >> 4);
      bf16x8 av[4], bv[4];
#pragma unroll
      for (int mi = 0; mi < 4; ++mi) {
        const int r = wr * 64 + mi * 16 + (lane & 15);
        av[mi] = *(const bf16x8*)(la + r * 128 + ((gk ^ (r & 7)) << 4));
      }
#pragma unroll
      for (int ni = 0; ni < 4; ++ni) {
        const int r = wc * 64 + ni * 16 + (lane & 15);
        bv[ni] = *(const bf16x8*)(lb + r * 128 + ((gk ^ (r & 7)) << 4));
      }
#pragma unroll
      for (int mi = 0; mi < 4; ++mi)
#pragma unroll
        for (int ni = 0; ni < 4; ++ni)
          acc[mi][ni] = __builtin_amdgcn_mfma_f32_16x16x32_bf16(av[mi], bv[ni], acc[mi][ni], 0, 0, 0);
    }
    __syncthreads();          // drains this iter's issued loads + barrier
  }

  const int cl = lane & 15;
  const int rg = (lane >> 4) << 2;
#pragma unroll
  for (int mi = 0; mi < 4; ++mi) {
#pragma unroll
    for (int ni = 0; ni < 4; ++ni) {
      const int gr = m0 + wr * 64 + mi * 16 + rg;
      const int gc = n0 + wc * 64 + ni * 16 + cl;
      float v0 = acc[mi][ni][0], v1 = acc[mi][ni][1];
      float v2 = acc[mi][ni][2], v3 = acc[mi][ni][3];
      if (Qadd) {
        v0 += bf2f(Qadd[(size_t)(gr + 0) * 512 + gc]);
        v1 += bf2f(Qadd[(size_t)(gr + 1) * 512 + gc]);
        v2 += bf2f(Qadd[(size_t)(gr + 2) * 512 + gc]);
        v3 += bf2f(Qadd[(size_t)(gr + 3) * 512 + gc]);
      }
      unsigned short h0 = f2bf(v0), h1 = f2bf(v1), h2 = f2bf(v2), h3 = f2bf(v3);
      if (Crm) {
        Crm[(size_t)(gr + 0) * 512 + gc] = h0;
        Crm[(size_t)(gr + 1) * 512 + gc] = h1;
        Crm[(size_t)(gr + 2) * 512 + gc] = h2;
        Crm[(size_t)(gr + 3) * 512 + gc] = h3;
      }
      if (Ct) {
        us4 tvec;
        tvec[0] = h0; tvec[1] = h1; tvec[2] = h2; tvec[3] = h3;
        *(us4*)(Ct + (size_t)gc * 512 + gr) = tvec;
      }
    }
  }
}

// ---------------------------------------------------------------------------
// S[b] = Cmat[b] @ Bmat[b]^T  (per graph, 512x512x256, fp32)
// 64x64 tiles; b = f&7 groups each graph onto one XCD.
// ---------------------------------------------------------------------------
__global__ __launch_bounds__(256) void gemm_nt_kernel(const float* __restrict__ Cm,
                                                      const float* __restrict__ Bm,
                                                      float* __restrict__ S) {
  const int f = blockIdx.y * gridDim.x + blockIdx.x;
  const int b = f & 7;
  const int tile = f >> 3;
  const float* Ab = Cm + (size_t)b * LNODE * DSTATE;
  const float* Bb = Bm + (size_t)b * LNODE * DSTATE;
  float* Sb = S + ((size_t)b << 18);
  const int m0 = (tile >> 3) << 6;
  const int n0 = (tile & 7) << 6;
  __shared__ float As[16][68];
  __shared__ float Bs[16][68];
  const int tid = threadIdx.x;
  const int tx = tid & 15, ty = tid >> 4;
  const int srow = tid >> 2, skq = tid & 3;
  float acc[4][4] = {};
  for (int k0 = 0; k0 < DSTATE; k0 += 16) {
    float4 a = *(const float4*)(Ab + (size_t)(m0 + srow) * DSTATE + k0 + skq * 4);
    As[skq * 4 + 0][srow] = a.x; As[skq * 4 + 1][srow] = a.y;
    As[skq * 4 + 2][srow] = a.z; As[skq * 4 + 3][srow] = a.w;
    float4 c = *(const float4*)(Bb + (size_t)(n0 + srow) * DSTATE + k0 + skq * 4);
    Bs[skq * 4 + 0][srow] = c.x; Bs[skq * 4 + 1][srow] = c.y;
    Bs[skq * 4 + 2][srow] = c.z; Bs[skq * 4 + 3][srow] = c.w;
    __syncthreads();
#pragma unroll
    for (int k = 0; k < 16; ++k) {
      float av[4], bv[4];
      *(float4*)(av) = *(const float4*)(&As[k][ty * 4]);
      *(float4*)(bv) = *(const float4*)(&Bs[k][tx * 4]);
#pragma unroll
      for (int i = 0; i < 4; ++i)
#pragma unroll
        for (int j = 0; j < 4; ++j)
          acc[i][j] = fmaf(av[i], bv[j], acc[i][j]);
    }
    __syncthreads();
  }
#pragma unroll
  for (int i = 0; i < 4; ++i) {
    float* sp = Sb + (size_t)(m0 + ty * 4 + i) * 512 + n0 + tx * 4;
    *(float4*)sp = make_float4(acc[i][0], acc[i][1], acc[i][2], acc[i][3]);
  }
}

// ---------------------------------------------------------------------------
// Fused make_M + final GEMM, K-split 4-way into PRIVATE partial buffers
// (no atomics): P[kg][bn][l][h] = sum_{t in kg} M[bn][l][t] * x[t][n*64+h]
// XCD swizzle: all 16 (ltile,kg) blocks of one bn share id%8.
// ---------------------------------------------------------------------------
__global__ __launch_bounds__(256) void final_fused_kernel(
    const unsigned short* __restrict__ Lm, const float* __restrict__ S,
    const float* __restrict__ dt, const float* __restrict__ x,
    float* __restrict__ P) {
  const int f = (blockIdx.z * gridDim.y + blockIdx.y) * gridDim.x + blockIdx.x;
  const int rres = f & 7;
  const int q = f >> 3;
  const int sub = q & 15;
  const int bn = ((q >> 4) << 3) + rres;
  const int ltile = sub & 3;
  const int kg = sub >> 2;
  const int n = bn & 3, b = bn >> 2;
  const unsigned short* Lb = Lm + ((size_t)bn << 18);
  const float* Sb = S + ((size_t)b << 18);
  const float* xb = x + (size_t)b * LNODE * DINNER + n * HEADD;
  const int m0 = ltile << 7;
  const int kbase = kg << 7;
  __shared__ float Ms[16][132];
  __shared__ float Xs[16][64];
  __shared__ float dts_all[128];
  const int tid = threadIdx.x;
  const int tx = tid & 15, ty = tid >> 4;
  if (tid < 128)
    dts_all[tid] = dt[(size_t)(b * 512 + kbase + tid) * 16 + n * 4 + 3];
  __syncthreads();
  float acc[8][4] = {};
  for (int kk0 = 0; kk0 < 128; kk0 += 16) {
    const int k0 = kbase + kk0;
#pragma unroll
    for (int s = 0; s < 2; ++s) {
      int fid = tid + s * 256;
      int m = fid >> 2, kq = fid & 3;
      us4 lm = *(const us4*)(Lb + (size_t)(m0 + m) * 512 + k0 + kq * 4);
      float4 sv = *(const float4*)(Sb + (size_t)(m0 + m) * 512 + k0 + kq * 4);
      Ms[kq * 4 + 0][m] = bf2f(lm[0]) * sv.x * dts_all[kk0 + kq * 4 + 0];
      Ms[kq * 4 + 1][m] = bf2f(lm[1]) * sv.y * dts_all[kk0 + kq * 4 + 1];
      Ms[kq * 4 + 2][m] = bf2f(lm[2]) * sv.z * dts_all[kk0 + kq * 4 + 2];
      Ms[kq * 4 + 3][m] = bf2f(lm[3]) * sv.w * dts_all[kk0 + kq * 4 + 3];
    }
    {
      int kk = tid >> 4, hq = tid & 15;
      float4 v = *(const float4*)(xb + (size_t)(k0 + kk) * DINNER + hq * 4);
      *(float4*)(&Xs[kk][hq * 4]) = v;
    }
    __syncthreads();
#pragma unroll
    for (int k = 0; k < 16; ++k) {
      float mv[8], xv[4];
      *(float4*)(mv)     = *(const float4*)(&Ms[k][ty * 8]);
      *(float4*)(mv + 4) = *(const float4*)(&Ms[k][ty * 8 + 4]);
      *(float4*)(xv)     = *(const float4*)(&Xs[k][tx * 4]);
#pragma unroll
      for (int i = 0; i < 8; ++i)
#pragma unroll
        for (int j = 0; j < 4; ++j)
          acc[i][j] = fmaf(mv[i], xv[j], acc[i][j]);
    }
    __syncthreads();
  }
  float* Pb = P + (((size_t)(kg * 32 + bn)) << 15);
#pragma unroll
  for (int i = 0; i < 8; ++i) {
    const int l = m0 + ty * 8 + i;
    *(float4*)(Pb + (size_t)l * 64 + tx * 4) =
        make_float4(acc[i][0], acc[i][1], acc[i][2], acc[i][3]);
  }
}

// ---------------------------------------------------------------------------
// Reduce partials + D*x residual, emit h*4+n interleave (coalesced float4).
// ---------------------------------------------------------------------------
__global__ __launch_bounds__(256) void reduce_out_kernel(
    const float* __restrict__ P, const float* __restrict__ x,
    const float* __restrict__ Dv, float* __restrict__ out) {
  int t = blockIdx.x * 256 + threadIdx.x;  // 8*512*64 = 262144
  int h = t & 63;
  int l = (t >> 6) & 511;
  int b = t >> 15;
  float4 v;
#pragma unroll
  for (int n = 0; n < 4; ++n) {
    int bn = b * 4 + n;
    float s = 0.0f;
#pragma unroll
    for (int kg = 0; kg < 4; ++kg)
      s += P[(((size_t)(kg * 32 + bn)) << 15) + (size_t)l * 64 + h];
    s += x[(size_t)(b * 512 + l) * 256 + n * 64 + h] * Dv[n];
    ((float*)&v)[n] = s;
  }
  *(float4*)(out + (size_t)(b * 512 + l) * 256 + h * 4) = v;
}

// ---------------------------------------------------------------------------
extern "C" void kernel_launch(void* const* d_in, const int* in_sizes, int n_in,
                              void* d_out, int out_size, void* d_ws, size_t ws_size,
                              hipStream_t stream) {
  const float* x        = (const float*)d_in[0];
  const float* Bmat     = (const float*)d_in[1];
  const float* Cmat     = (const float*)d_in[2];
  const float* dt       = (const float*)d_in[3];
  const float* dt_edge  = (const float*)d_in[4];
  const float* dt_bias  = (const float*)d_in[5];
  const float* Dv       = (const float*)d_in[6];
  const int* edge_index = (const int*)d_in[7];
  float* out = (float*)d_out;

  // Workspace: 6 rotating bf16 slots of 16.78 MB + colsum. Peak ~100.7 MB.
  char* wsb = (char*)d_ws;
  const size_t SL = 16777216;
  unsigned short* sA = (unsigned short*)(wsb + 0 * SL);
  unsigned short* sB = (unsigned short*)(wsb + 1 * SL);
  unsigned short* sC = (unsigned short*)(wsb + 2 * SL);
  unsigned short* sD = (unsigned short*)(wsb + 3 * SL);
  unsigned short* sE = (unsigned short*)(wsb + 4 * SL);
  unsigned short* sF = (unsigned short*)(wsb + 5 * SL);
  float* G      = (float*)(wsb + 3 * SL);   // 32 MB fp32, dead after conv
  float* Sbuf   = (float*)(wsb + 5 * SL);   // 8.4 MB fp32, written after L3
  float* Pbuf   = (float*)(wsb + 3 * SL);   // 16.8 MB fp32, written after L4
  float* colsum = (float*)(wsb + 6 * SL);   // 64 KB

  hipMemsetAsync(G, 0, 33554432, stream);
  hipMemsetAsync(colsum, 0, 32 * 512 * 4, stream);
  scatter_edges_kernel<<<1024, 256, 0, stream>>>(dt, dt_edge, dt_bias, edge_index, G, colsum);
  conv_kernel<<<dim3(256, 32), 256, 0, stream>>>(G, colsum, dt, dt_bias, sA, sB, sC);

  // Doubling chain, paired so each stage's two GEMMs are independent:
  //   F1=P@P; F2=F1@F1 || U0=Q0@F1t+Q0; F3=F2@F2 || U1=U0@F2t+U0;
  //   F4=F3@F3 (t only) || U2=U1@F3t+U1; U3=U2@F4t+U2  (= Lm)
  dim3 g1(16, 32, 1), g2(16, 32, 2);
  gemm_pair_kernel<<<g1, 256, 0, stream>>>(sA, sB, sD, sE, nullptr,
                                           nullptr, nullptr, nullptr, nullptr, nullptr);
  gemm_pair_kernel<<<g2, 256, 0, stream>>>(sD, sE, sA, sB, nullptr,
                                           sC, sE, sF, nullptr, sC);
  gemm_pair_kernel<<<g2, 256, 0, stream>>>(sA, sB, sC, sD, nullptr,
                                           sF, sB, sE, nullptr, sF);
  gemm_nt_kernel<<<dim3(64, 8), 256, 0, stream>>>(Cmat, Bmat, Sbuf);
  gemm_pair_kernel<<<g2, 256, 0, stream>>>(sC, sD, nullptr, sA, nullptr,
                                           sE, sD, sB, nullptr, sE);
  gemm_pair_kernel<<<g1, 256, 0, stream>>>(sB, sA, sC, nullptr, sB,
                                           nullptr, nullptr, nullptr, nullptr, nullptr);

  final_fused_kernel<<<dim3(4, 4, 32), 256, 0, stream>>>(sC, Sbuf, dt, x, Pbuf);
  reduce_out_kernel<<<1024, 256, 0, stream>>>(Pbuf, x, Dv, out);
}